// Round 7
// baseline (117.258 us; speedup 1.0000x reference)
//
#include <hip/hip_runtime.h>

// Fully fused 3-level db4 wavedec (periodization) over (B=64, N=4096, F=64) f32.
// v7: T3=32 + chunked register prefetch. v6 validated the byte-throughput
// model (time ~ instruction-level bytes at ~5.2 TB/s): T3=16's 0.88x bytes
// gave 0.90x time. v7 cuts amp further: 298 rows read / 256 produced = 1.16x
// -> 145 MB (0.93x of v6). This drops occupancy to 1 wave/SIMD (1024 tiles,
// one per wave), so v4's chunked triple-buffered register prefetch (null at
// 2 waves/SIMD where TLP covered latency) is now load-bearing: 32-row chunks
// issued 2-3 chunks (~1500 cy) ahead keep 32-96 loads in flight per wave.
//
// c[k] = sum_j filt[j] * x[(2k+1-j) mod N]  ==  sum_m w[m]*filtR[m],
// where w[m] = x[(2k-6+m) mod N] and filtR[m] = filt[7-m].
// Row t (t=0..297) = (tbase + t) & 4095, tbase = 8*K3 - 42.
// Chunk c = rows [32c, 32c+32) (chunk 9: 10 rows). Initial window = chunk0[0..7];
// step s (1..145) consumes rows t = 2s+6, 2s+7; chunk c serves s in [16c-3, 16c+12].
//
// Output rows: [0,512)=cA3, [512,1024)=cD3, [1024,2048)=cD2, [2048,4096)=cD1.
// Own output ranges never wrap (i1 in [4K3,4K3+128) < 2048, etc) -> unmasked stores.

__global__ __launch_bounds__(256, 1) void dwt3_fused_v7(
    const float* __restrict__ in,   // (64, 4096, 64)
    float* __restrict__ out)        // (64, 4096, 64)
{
    // reversed filters (filtR[m] = filt[7-m])
    const float LOR[8] = { 0.23037781330885523f,   0.7148465705525415f,
                           0.6308807679295904f,   -0.02798376941698385f,
                          -0.18703481171888114f,   0.030841381835986965f,
                           0.032883011666982945f, -0.010597401784997278f};
    const float HIR[8] = {-0.010597401784997278f, -0.032883011666982945f,
                           0.030841381835986965f,  0.18703481171888114f,
                          -0.02798376941698385f,  -0.6308807679295904f,
                           0.7148465705525415f,   -0.23037781330885523f};

    // XCD-aware swizzle: 256 blocks, 8 XCDs, 32 contiguous blocks per XCD.
    const int bid  = blockIdx.x;
    const int swz  = (bid & 7) * 32 + (bid >> 3);

    const int f    = threadIdx.x & 63;             // one f-column per lane
    const int wv   = threadIdx.x >> 6;             // wave within block (0..3)
    const int b    = swz >> 2;                     // 64 batches (4 blocks each)
    const int tile = (swz & 3) * 4 + wv;           // 16 tiles of T3=32 per batch
    const int K3   = tile * 32;

    const float* inB  = in  + (size_t)b * 4096 * 64 + f;
    float*       outB = out + (size_t)b * 4096 * 64 + f;

    const int i1s   = 4 * K3 - 18;   // first level-1 index produced (even)
    const int tbase = 2 * i1s - 6;   // row offset of t=0

    float bufA[32], bufB[32], bufC[32], bufD[10];

    #define ISSUE(BUF, C, N)                                                    \
        _Pragma("unroll")                                                       \
        for (int j = 0; j < (N); ++j) {                                         \
            BUF[j] = inB[(size_t)((tbase + 32 * (C) + j) & 4095) * 64];         \
        }

    // Prologue: 3 chunks (96 rows) in flight before any compute.
    ISSUE(bufA, 0, 32)
    ISSUE(bufB, 1, 32)
    ISSUE(bufC, 2, 32)

    float w0[8];
    float w1[8] = {0,0,0,0,0,0,0,0};
    float w2[8] = {0,0,0,0,0,0,0,0};
    #pragma unroll
    for (int m = 0; m < 8; ++m) w0[m] = bufA[m];

    // One cascade step (s >= 1), consuming the two new rows X0, X1.
    #define STEP(S, X0, X1) {                                                  \
        const int i1 = i1s + (S);                                              \
        _Pragma("unroll")                                                      \
        for (int m = 0; m < 6; ++m) w0[m] = w0[m + 2];                         \
        w0[6] = (X0); w0[7] = (X1);                                            \
        float a1 = 0.f;                                                        \
        _Pragma("unroll")                                                      \
        for (int m = 0; m < 8; ++m) a1 = fmaf(w0[m], LOR[m], a1);              \
        if ((S) >= 18) {                                                       \
            float d1 = 0.f;                                                    \
            _Pragma("unroll")                                                  \
            for (int m = 0; m < 8; ++m) d1 = fmaf(w0[m], HIR[m], d1);          \
            outB[(size_t)(2048 + i1) * 64] = d1;                               \
        }                                                                      \
        _Pragma("unroll")                                                      \
        for (int m = 0; m < 7; ++m) w1[m] = w1[m + 1];                         \
        w1[7] = a1;                                                            \
        if (((S) & 1) && (S) >= 7) {                                           \
            const int i2 = 2 * K3 + ((S) - 19) / 2;                            \
            float a2 = 0.f;                                                    \
            _Pragma("unroll")                                                  \
            for (int m = 0; m < 8; ++m) a2 = fmaf(w1[m], LOR[m], a2);          \
            if ((S) >= 19) {                                                   \
                float d2 = 0.f;                                                \
                _Pragma("unroll")                                              \
                for (int m = 0; m < 8; ++m) d2 = fmaf(w1[m], HIR[m], d2);      \
                outB[(size_t)(1024 + i2) * 64] = d2;                           \
            }                                                                  \
            _Pragma("unroll")                                                  \
            for (int m = 0; m < 7; ++m) w2[m] = w2[m + 1];                     \
            w2[7] = a2;                                                        \
            if ((S) >= 21 && (((S) - 21) & 3) == 0) {                          \
                const int i3 = K3 + ((S) - 21) / 4;                            \
                float a3 = 0.f, d3 = 0.f;                                      \
                _Pragma("unroll")                                              \
                for (int m = 0; m < 8; ++m) {                                  \
                    a3 = fmaf(w2[m], LOR[m], a3);                              \
                    d3 = fmaf(w2[m], HIR[m], d3);                              \
                }                                                              \
                outB[(size_t)i3 * 64]         = a3;                            \
                outB[(size_t)(512 + i3) * 64] = d3;                            \
            }                                                                  \
        }                                                                      \
    }

    // ---- step 0: window just initialized; a1 only (s=0: even, < 18)
    {
        float a1 = 0.f;
        #pragma unroll
        for (int m = 0; m < 8; ++m) a1 = fmaf(w0[m], LOR[m], a1);
        #pragma unroll
        for (int m = 0; m < 7; ++m) w1[m] = w1[m + 1];
        w1[7] = a1;
    }

    // steps 1..12 consume bufA[8..31] (chunk 0)
    #pragma unroll
    for (int s = 1; s <= 12; ++s) STEP(s, bufA[2 * s + 6], bufA[2 * s + 7])

    ISSUE(bufA, 3, 32)
    #pragma unroll
    for (int s = 13; s <= 28; ++s) STEP(s, bufB[2 * s + 6 - 32], bufB[2 * s + 7 - 32])

    ISSUE(bufB, 4, 32)
    #pragma unroll
    for (int s = 29; s <= 44; ++s) STEP(s, bufC[2 * s + 6 - 64], bufC[2 * s + 7 - 64])

    ISSUE(bufC, 5, 32)
    #pragma unroll
    for (int s = 45; s <= 60; ++s) STEP(s, bufA[2 * s + 6 - 96], bufA[2 * s + 7 - 96])

    ISSUE(bufA, 6, 32)
    #pragma unroll
    for (int s = 61; s <= 76; ++s) STEP(s, bufB[2 * s + 6 - 128], bufB[2 * s + 7 - 128])

    ISSUE(bufB, 7, 32)
    #pragma unroll
    for (int s = 77; s <= 92; ++s) STEP(s, bufC[2 * s + 6 - 160], bufC[2 * s + 7 - 160])

    ISSUE(bufC, 8, 32)
    #pragma unroll
    for (int s = 93; s <= 108; ++s) STEP(s, bufA[2 * s + 6 - 192], bufA[2 * s + 7 - 192])

    ISSUE(bufD, 9, 10)                             // tail chunk (rows 288..297)
    #pragma unroll
    for (int s = 109; s <= 124; ++s) STEP(s, bufB[2 * s + 6 - 224], bufB[2 * s + 7 - 224])

    #pragma unroll
    for (int s = 125; s <= 140; ++s) STEP(s, bufC[2 * s + 6 - 256], bufC[2 * s + 7 - 256])

    #pragma unroll
    for (int s = 141; s <= 145; ++s) STEP(s, bufD[2 * s + 6 - 288], bufD[2 * s + 7 - 288])

    #undef STEP
    #undef ISSUE
}

extern "C" void kernel_launch(void* const* d_in, const int* in_sizes, int n_in,
                              void* d_out, int out_size, void* d_ws, size_t ws_size,
                              hipStream_t stream) {
    (void)in_sizes; (void)n_in; (void)out_size; (void)d_ws; (void)ws_size;
    const float* x = (const float*)d_in[0];
    float* out = (float*)d_out;
    // 64 batches * 4 blocks (4 waves/block, 1 tile/wave, T3=32) = 256 blocks
    dwt3_fused_v7<<<256, 256, 0, stream>>>(x, out);
}

// Round 8
// 113.257 us; speedup vs baseline: 1.0353x; 1.0353x over previous
//
#include <hip/hip_runtime.h>

// Fully fused 3-level db4 wavedec (periodization) over (B=64, N=4096, F=64) f32.
// v6-final (revert from v7): T3=16, one tile per wave, scalar f32 per lane,
// 2 waves/SIMD. This is the measured optimum of the byte/occupancy trade:
//   T3=8  (1.66x read amp, 178 MB issued) ~33.5 us
//   T3=16 (1.33x,          156 MB issued) ~30.7 us  <-- best
//   T3=32 (1.16x, 1 wave/SIMD)            ~34   us  (occupancy cliff, v7)
// Session evidence: issued-byte model at ~5.15 TB/s explains all 7 variants;
// width (v2), TLP (v3), 48-deep MLP (v4), store-order (v5) all null;
// byte cuts (v6) the only real lever, exhausted at this occupancy.
// LDS halo-dedup rejected: every variant needs >=100 KB LDS/block -> 1
// wave/SIMD regime measured (v7) at +10% cost for a -14% byte saving.
//
// c[k] = sum_j filt[j] * x[(2k+1-j) mod N]  ==  sum_m w[m]*filtR[m],
// where w[m] = x[(2k-6+m) mod N] and filtR[m] = filt[7-m].
//
// Output rows: [0,512)=cA3, [512,1024)=cD3, [1024,2048)=cD2, [2048,4096)=cD1.
// Own output ranges never wrap (i1<2048, i2<1024, i3<512) -> no mask on stores.
// Input rows span [8K3-42, 8K3+128) -> masked & 4095 (wraps at both ends).

__global__ __launch_bounds__(256, 2) void dwt3_fused_v6(
    const float* __restrict__ in,   // (64, 4096, 64)
    float* __restrict__ out)        // (64, 4096, 64)
{
    // reversed filters (filtR[m] = filt[7-m])
    const float LOR[8] = { 0.23037781330885523f,   0.7148465705525415f,
                           0.6308807679295904f,   -0.02798376941698385f,
                          -0.18703481171888114f,   0.030841381835986965f,
                           0.032883011666982945f, -0.010597401784997278f};
    const float HIR[8] = {-0.010597401784997278f, -0.032883011666982945f,
                           0.030841381835986965f,  0.18703481171888114f,
                          -0.02798376941698385f,  -0.6308807679295904f,
                           0.7148465705525415f,   -0.23037781330885523f};

    // XCD-aware swizzle: 512 blocks, 8 XCDs, 64 contiguous blocks per XCD.
    const int bid  = blockIdx.x;
    const int swz  = (bid & 7) * 64 + (bid >> 3);

    const int f    = threadIdx.x & 63;             // one f-column per lane
    const int wv   = threadIdx.x >> 6;             // wave within block (0..3)
    const int b    = swz >> 3;                     // 64 batches
    const int tile = (swz & 7) * 4 + wv;           // 32 tiles of T3=16 per batch
    const int K3   = tile * 16;

    const float* inB  = in  + (size_t)b * 4096 * 64 + f;
    float*       outB = out + (size_t)b * 4096 * 64 + f;

    const int i1s = 4 * K3 - 18;   // first level-1 index produced (even)

    float w0[8];                       // rolling window x[(2*i1-6 .. 2*i1+1) mod N]
    float w1[8] = {0,0,0,0,0,0,0,0};   // last 8 cA1 values
    float w2[8] = {0,0,0,0,0,0,0,0};   // last 8 cA2 values

    #pragma unroll
    for (int m = 0; m < 8; ++m) {
        const int r = (2 * i1s - 6 + m) & 4095;
        w0[m] = inB[(size_t)r * 64];
    }

    #pragma unroll
    for (int s = 0; s < 82; ++s) {
        const int i1 = i1s + s;
        if (s > 0) {
            #pragma unroll
            for (int m = 0; m < 6; ++m) w0[m] = w0[m + 2];
            const int ra = (2 * i1)     & 4095;
            const int rb = (2 * i1 + 1) & 4095;
            w0[6] = inB[(size_t)ra * 64];
            w0[7] = inB[(size_t)rb * 64];
        }

        // ---- level 1 ----
        float a1 = 0.f;
        #pragma unroll
        for (int m = 0; m < 8; ++m) a1 = fmaf(w0[m], LOR[m], a1);
        if (s >= 18) {                       // i1 in own range [4K3, 4K3+64)
            float d1 = 0.f;
            #pragma unroll
            for (int m = 0; m < 8; ++m) d1 = fmaf(w0[m], HIR[m], d1);
            outB[(size_t)(2048 + i1) * 64] = d1;
        }
        #pragma unroll
        for (int m = 0; m < 7; ++m) w1[m] = w1[m + 1];
        w1[7] = a1;

        // ---- level 2: emit when i1 = 2*i2+1 (s odd) and window full ----
        if ((s & 1) && s >= 7) {
            const int i2 = 2 * K3 + (s - 19) / 2;   // exact for odd s
            float a2 = 0.f;
            #pragma unroll
            for (int m = 0; m < 8; ++m) a2 = fmaf(w1[m], LOR[m], a2);
            if (s >= 19) {                   // i2 in own range [2K3, 2K3+32)
                float d2 = 0.f;
                #pragma unroll
                for (int m = 0; m < 8; ++m) d2 = fmaf(w1[m], HIR[m], d2);
                outB[(size_t)(1024 + i2) * 64] = d2;
            }
            #pragma unroll
            for (int m = 0; m < 7; ++m) w2[m] = w2[m + 1];
            w2[7] = a2;

            // ---- level 3: emit when i2 = 2*i3+1 and window full ----
            if (s >= 21 && ((s - 21) & 3) == 0) {
                const int i3 = K3 + (s - 21) / 4;    // own range [K3, K3+16)
                float a3 = 0.f, d3 = 0.f;
                #pragma unroll
                for (int m = 0; m < 8; ++m) {
                    a3 = fmaf(w2[m], LOR[m], a3);
                    d3 = fmaf(w2[m], HIR[m], d3);
                }
                outB[(size_t)i3 * 64]         = a3;
                outB[(size_t)(512 + i3) * 64] = d3;
            }
        }
    }
}

extern "C" void kernel_launch(void* const* d_in, const int* in_sizes, int n_in,
                              void* d_out, int out_size, void* d_ws, size_t ws_size,
                              hipStream_t stream) {
    (void)in_sizes; (void)n_in; (void)out_size; (void)d_ws; (void)ws_size;
    const float* x = (const float*)d_in[0];
    float* out = (float*)d_out;
    // 64 batches * 8 block-groups (4 waves/block, 1 tile/wave, T3=16) = 512 blocks
    dwt3_fused_v6<<<512, 256, 0, stream>>>(x, out);
}